// Round 9
// baseline (93.270 us; speedup 1.0000x reference)
//
#include <hip/hip_runtime.h>
#include <hip/hip_fp16.h>

// Problem: Topo_60653528154131
//   x:[256,3,256,25] f32, centres:[64,2] f32, sharpness:[64,2] f32 -> out:[64] f32
//
// Pipeline (3 kernels; separate graph nodes are the cheap grid barrier — measured
// cooperative grid.sync() ~26 us/barrier on this 8-XCD part, R7):
//   K1 k_mean : mean_{c,t} x[n] -> feat[n,:] directly (feat is per-sample!),
//               Mp INF-init, done=0. 1024 thr / 800 active (load-width for HBM).
//   K2 k_dist : stage featG, D2 row -> D16, row-min edge key -> rowKeyG,
//               block 0 -> feat min/max -> mm.
//   K3 k_tail : 256 blocks. Each block deterministically replays Boruvka round-1
//               hooking from rowKeyG (ballot-rank renumber -> identical cmap AND
//               identical round-1 deaths in every block), folds its row of D16
//               into Mp via agent-scope atomicMin, then LAST block (atomic done
//               counter, acq_rel — no spinning, schedule-independent) reads Mp
//               with agent-scope atomic loads (XCD-L2-stale-proof), runs Boruvka
//               rounds 2+ in LDS, deaths = sqrt(D2)/(max-min), structure layer.
//
// ws layout:
//   featG [6400]  f32 @ 0
//   mm    [2]     u32 @ 25600   (min,max of feat as ordered-uint bits; feat>=0)
//   rowKeyG [256] u32 @ 28672
//   doneG [1]     u32 @ 30720
//   D16   [65536] u16 @ 65536   (fp16 bits of D^2)
//   Mp    [128*132] u32 @ 196608 (round-1 contracted matrix, stride 132)

#define WS_FEAT 0
#define WS_MM   25600
#define WS_RK   28672
#define WS_DONE 30720
#define WS_D16  65536
#define WS_MP   196608

#define INF32 0xFFFFFFFFu
#define MPSTR 132

// ---------------- K1: mean -> feat (per-sample) + Mp INF-init + done=0 ----------
__global__ void __launch_bounds__(1024) k_mean(const float* __restrict__ x,
                                               float* __restrict__ featG,
                                               unsigned int* __restrict__ Mp,
                                               unsigned int* __restrict__ doneG) {
    const int n = blockIdx.x;
    const int tid = threadIdx.x;
    if (tid < 66) Mp[n * 66 + tid] = INF32;   // 256*66 = 16896 = 128*132 exactly
    if (n == 0 && tid == 1023) *doneG = 0;    // reset last-block counter each launch
    __shared__ float sums[25];
    if (tid < 25) sums[tid] = 0.0f;
    __syncthreads();
    if (tid < 800) {   // 19200 floats = 800 lanes x 6 float4; stride 3200 % 25 == 0
        const float* base = x + (long)n * 19200 + 4 * tid;
        float a0 = 0.f, a1 = 0.f, a2 = 0.f, a3 = 0.f;
        #pragma unroll
        for (int i = 0; i < 6; ++i) {
            float4 v = *reinterpret_cast<const float4*>(base + 3200 * i);
            a0 += v.x; a1 += v.y; a2 += v.z; a3 += v.w;
        }
        const int v0 = (4 * tid) % 25;
        atomicAdd(&sums[v0], a0);
        atomicAdd(&sums[(v0 + 1) % 25], a1);
        atomicAdd(&sums[(v0 + 2) % 25], a2);
        atomicAdd(&sums[(v0 + 3) % 25], a3);
    }
    __syncthreads();
    if (tid < 25) {
        // feat[n][w] = ||m - m_w|| = sqrt(S2 - 2 r_w S1 + 25 r_w^2), r = sums/768
        // (same f32 ops/order as the old k_dist path -> bit-identical)
        float S1 = 0.f, S2 = 0.f;
        #pragma unroll
        for (int v = 0; v < 25; ++v) {
            const float rv = sums[v] * (1.0f / 768.0f);
            S1 += rv; S2 += rv * rv;
        }
        const float rw = sums[tid] * (1.0f / 768.0f);
        float q = S2 - 2.f * rw * S1 + 25.f * rw * rw;
        q = fmaxf(q, 0.f);
        featG[n * 25 + tid] = sqrtf(q);
    }
}

// wave64 min-reduce step via DPP: invalid lanes keep old=INF
template <int CTRL>
__device__ __forceinline__ unsigned int dpp_min_step(unsigned int v) {
    unsigned int t = (unsigned int)__builtin_amdgcn_update_dpp(
        (int)0xFFFFFFFF, (int)v, CTRL, 0xF, 0xF, false);
    return (t < v) ? t : v;
}

// ---------------- K2: D2 row + row-min key + minmax (block 0) ----------------
__global__ void __launch_bounds__(256) k_dist(const float* __restrict__ featG,
                                              unsigned short* __restrict__ D16,
                                              unsigned int* __restrict__ rowKeyG,
                                              unsigned int* __restrict__ mm) {
    __shared__ float featS[6400];
    __shared__ unsigned int bmin, bmax;
    __shared__ unsigned int wred[4];
    const int i = blockIdx.x;
    const int t = threadIdx.x;
    if (t == 0) { bmin = 0x7F800000u; bmax = 0u; }
    #pragma unroll
    for (int it = 0; it < 7; ++it) {   // stage feat: 1600 float4
        int o = it * 256 + t;
        if (o < 1600) reinterpret_cast<float4*>(featS)[o] =
            reinterpret_cast<const float4*>(featG)[o];
    }
    __syncthreads();
    if (i == 0) {   // block 0 scans all 6400 feats for global min/max
        float fmn = 1e30f, fmx = -1e30f;
        #pragma unroll
        for (int w = 0; w < 25; ++w) {
            const float f = featS[t * 25 + w];
            fmn = fminf(fmn, f); fmx = fmaxf(fmx, f);
        }
        atomicMin(&bmin, __float_as_uint(fmn));  // f>=0: uint order == float order
        atomicMax(&bmax, __float_as_uint(fmx));
        __syncthreads();
        if (t == 0) { mm[0] = bmin; mm[1] = bmax; }
    }
    float fi[25];
    #pragma unroll
    for (int v = 0; v < 25; ++v) fi[v] = featS[i * 25 + v];
    float s = 0.f;
    #pragma unroll
    for (int v = 0; v < 25; ++v) { float d = fi[v] - featS[t * 25 + v]; s += d * d; }
    const unsigned int w16 = (unsigned int)__half_as_ushort(__float2half(s));
    D16[i * 256 + t] = (unsigned short)w16;
    const unsigned int lo = (i < t) ? i : t, hi = (i < t) ? t : i;
    unsigned int key = (t == i) ? INF32 : ((w16 << 16) | (lo << 8) | hi);
    key = dpp_min_step<0x111>(key);
    key = dpp_min_step<0x112>(key);
    key = dpp_min_step<0x114>(key);
    key = dpp_min_step<0x118>(key);
    key = dpp_min_step<0x142>(key);
    key = dpp_min_step<0x143>(key);
    if ((t & 63) == 63) wred[t >> 6] = key;
    __syncthreads();
    if (t == 0) {
        unsigned int b0 = wred[0] < wred[1] ? wred[0] : wred[1];
        unsigned int b1 = wred[2] < wred[3] ? wred[2] : wred[3];
        rowKeyG[i] = b0 < b1 ? b0 : b1;
    }
}

// ---------------- wave0 Boruvka phase (DETERMINISTIC) ----------------
// hook -> 2-cycle break (death record) -> async pointer jump -> ballot-rank
// renumber. Deterministic: identical cmap/nc/deaths in every block.
// Wave-0 lanes only; no __syncthreads inside.
__device__ __forceinline__ void wave0_phase(int n, int lane,
        unsigned int* rowKeyS, unsigned char* parentS, unsigned char* newidS,
        unsigned char* cmapS, float* deaths, unsigned int* ncS, unsigned int* dcS) {
    unsigned int par[4];
    #pragma unroll
    for (int s = 0; s < 4; ++s) {         // hook
        const int i = lane + 64 * s;
        if (i < n) {
            const unsigned int rk = rowKeyS[i];
            const unsigned int u = (rk >> 8) & 0xFFu, v = rk & 0xFFu;
            unsigned int p = (u == (unsigned int)i) ? v : u;
            if (rk == INF32) p = (unsigned int)i;  // safety; complete graph: unused
            par[s] = p;
            parentS[i] = (unsigned char)p;
        }
    }
    #pragma unroll
    for (int s = 0; s < 4; ++s) {         // break mutual 2-cycles
        const int i = lane + 64 * s;
        if (i < n) {
            const unsigned int p = par[s];
            if (p != (unsigned int)i) {
                if (parentS[p] == (unsigned char)i && (unsigned int)i < p) {
                    parentS[i] = (unsigned char)i;   // winner stays root, no death
                } else {
                    const unsigned int d = atomicAdd(dcS, 1u);
                    const unsigned int rk = rowKeyS[i];
                    deaths[d] = sqrtf(__half2float(__ushort_as_half(
                        (unsigned short)(rk >> 16))));
                }
            }
        }
    }
    for (;;) {                            // async pointer jump (deterministic fixpoint)
        bool ch = false;
        #pragma unroll
        for (int s = 0; s < 4; ++s) {
            const int i = lane + 64 * s;
            if (i < n) {
                const unsigned char p0 = parentS[i];
                const unsigned char np = parentS[p0];
                if (np != p0) { ch = true; parentS[i] = np; }
            }
        }
        if (__ballot(ch) == 0ull) break;
    }
    // ballot-rank renumber; below = lanes strictly below me (well-defined, lane<=63)
    bool isr[4];
    #pragma unroll
    for (int s = 0; s < 4; ++s) {
        const int i = lane + 64 * s;
        isr[s] = (i < n) && (parentS[i] == (unsigned char)i);
    }
    unsigned int base = 0;
    const unsigned long long below = (1ull << lane) - 1ull;
    #pragma unroll
    for (int s = 0; s < 4; ++s) {
        const unsigned long long mask = __ballot(isr[s]);   // uniform execution
        if (isr[s]) {
            const int i = lane + 64 * s;
            newidS[i] = (unsigned char)(base + __popcll(mask & below));
        }
        base += (unsigned int)__popcll(mask);
    }
    if (lane == 0) *ncS = base;
    #pragma unroll
    for (int s = 0; s < 4; ++s) {
        const int i = lane + 64 * s;
        if (i < n) cmapS[i] = newidS[parentS[i]];
    }
}

// ---------------- K3: contraction fold + last-block MST + structure layer --------
#define SA 132   // u32 stride, buffer A (cap 128 rows)
#define SB 68    // u32 stride, buffer B (cap 64 rows)
#define OFF_B (128 * SA)

__global__ void __launch_bounds__(1024) k_tail(const unsigned short* __restrict__ D16g,
                                               const unsigned int* __restrict__ rowKeyG,
                                               unsigned int* __restrict__ Mp,
                                               unsigned int* __restrict__ doneG,
                                               const unsigned int* __restrict__ mm,
                                               const float* __restrict__ centres,
                                               const float* __restrict__ sharp,
                                               float* __restrict__ out) {
    __shared__ unsigned int Mb[128 * SA + 64 * SB];   // 85 KB ping-pong
    __shared__ unsigned int rowKeyS[256];
    __shared__ unsigned char parentS[256], newidS[256], cmapS[256];
    __shared__ unsigned int ncS, dcS, lastS;
    __shared__ float deaths[256];
    __shared__ float outpart[1024];
    const int tid = threadIdx.x;
    const int b = blockIdx.x;

    // replay round-1 hook (deterministic -> every block holds round-1 deaths, n)
    if (tid < 256) rowKeyS[tid] = rowKeyG[tid];
    if (tid == 0) dcS = 0;
    __syncthreads();
    if (tid < 64)
        wave0_phase(256, tid, rowKeyS, parentS, newidS, cmapS, deaths, &ncS, &dcS);
    __syncthreads();

    // fold row b into Mp (agent-scope atomicMin: RMW at coherent point)
    if (tid < 256) {
        const unsigned int ca = cmapS[b];
        const unsigned int cb = cmapS[tid];
        if (ca != cb) {
            const unsigned int w16 = (unsigned int)D16g[b * 256 + tid];
            const unsigned int lo = ca < cb ? ca : cb;
            const unsigned int hi = ca < cb ? cb : ca;
            atomicMin(&Mp[ca * MPSTR + cb], (w16 << 16) | (lo << 8) | hi);
        }
    }
    __syncthreads();   // drains vmcnt: this block's folds complete before the count

    // last-block-takes-over (no spinning, schedule-independent)
    if (tid == 0) {
        const unsigned int old = __hip_atomic_fetch_add(
            doneG, 1u, __ATOMIC_ACQ_REL, __HIP_MEMORY_SCOPE_AGENT);
        lastS = (old == 255u) ? 1u : 0u;
    }
    __syncthreads();
    if (!lastS) return;

    // ---- last block only: Boruvka rounds 2+ on contracted matrix ----
    int n = (int)ncS;
    // agent-scope atomic loads of Mp: immune to stale per-XCD L2 lines
    for (int idx = tid; idx < n * SA; idx += 1024)
        Mb[idx] = __hip_atomic_load(&Mp[idx], __ATOMIC_RELAXED,
                                    __HIP_MEMORY_SCOPE_AGENT);
    __syncthreads();

    int srcOff = 0, srcStr = SA, dstOff = OFF_B, dstStr = SB;
    for (int round = 0; round < 12 && n > 1; ++round) {   // hang guard
        if (tid < n) rowKeyS[tid] = INF32;
        __syncthreads();
        if (tid < 8 * n) {                 // scan: 8 threads per row
            const int a = tid >> 3, sub = tid & 7;
            const unsigned int* row = &Mb[srcOff + a * srcStr];
            unsigned int best = INF32;
            for (int b2 = sub; b2 < n; b2 += 8) {
                const unsigned int v = row[b2];
                best = v < best ? v : best;
            }
            if (best != INF32) atomicMin(&rowKeyS[a], best);
        }
        __syncthreads();
        if (tid < 64)
            wave0_phase(n, tid, rowKeyS, parentS, newidS, cmapS, deaths, &ncS, &dcS);
        __syncthreads();
        const int nc = (int)ncS;
        if (nc > 1) {                      // contract src -> dst
            for (int w = tid; w < nc * dstStr; w += 1024) Mb[dstOff + w] = INF32;
            __syncthreads();
            if (tid < 8 * n) {
                const int a = tid >> 3, sub = tid & 7;
                const unsigned int ca = cmapS[a];
                const unsigned int* row = &Mb[srcOff + a * srcStr];
                for (int b2 = sub; b2 < n; b2 += 8) {
                    const unsigned int cb = cmapS[b2];
                    const unsigned int v = row[b2];
                    if (ca != cb && v != INF32) {
                        const unsigned int lo = ca < cb ? ca : cb;
                        const unsigned int hi = ca < cb ? cb : ca;
                        atomicMin(&Mb[dstOff + ca * dstStr + cb],
                                  (v & 0xFFFF0000u) | (lo << 8) | hi);
                    }
                }
            }
            __syncthreads();
        }
        const int t1 = srcOff; srcOff = dstOff; dstOff = t1;
        const int t2 = srcStr; srcStr = dstStr; dstStr = t2;
        n = nc;
    }

    // structure-element layer: out[k] = sum_i exp(-c0^2 s0^2 - (d_i-c1)^2 s1^2)
    const float mn = __uint_as_float(mm[0]);
    const float mx = __uint_as_float(mm[1]);
    const float inv = 1.0f / (mx - mn);
    const int k = tid & 63;
    const int part = tid >> 6;
    const float c0 = centres[2 * k], c1 = centres[2 * k + 1];
    const float s0 = sharp[2 * k],   s1 = sharp[2 * k + 1];
    const float t0 = c0 * c0 * s0 * s0;
    const float s1sq = s1 * s1;
    float acc = 0.f;
    for (int idx = part; idx < 255; idx += 16) {
        const float d = deaths[idx] * inv - c1;
        acc += __expf(-(t0 + d * d * s1sq));
    }
    outpart[tid] = acc;
    __syncthreads();
    if (tid < 64) {
        float s = 0.f;
        #pragma unroll
        for (int pp = 0; pp < 16; ++pp) s += outpart[tid + 64 * pp];
        out[tid] = s;
    }
}

extern "C" void kernel_launch(void* const* d_in, const int* in_sizes, int n_in,
                              void* d_out, int out_size, void* d_ws, size_t ws_size,
                              hipStream_t stream) {
    const float* x       = (const float*)d_in[0];
    const float* centres = (const float*)d_in[1];
    const float* sharp   = (const float*)d_in[2];
    float* out = (float*)d_out;
    char* ws = (char*)d_ws;
    float*          featG = (float*)(ws + WS_FEAT);
    unsigned int*   mm    = (unsigned int*)(ws + WS_MM);
    unsigned int*   rk    = (unsigned int*)(ws + WS_RK);
    unsigned int*   done  = (unsigned int*)(ws + WS_DONE);
    unsigned short* D16   = (unsigned short*)(ws + WS_D16);
    unsigned int*   Mp    = (unsigned int*)(ws + WS_MP);

    k_mean<<<256, 1024, 0, stream>>>(x, featG, Mp, done);
    k_dist<<<256, 256, 0, stream>>>(featG, D16, rk, mm);
    k_tail<<<256, 1024, 0, stream>>>(D16, rk, Mp, done, mm, centres, sharp, out);
}

// Round 10
// 93.051 us; speedup vs baseline: 1.0024x; 1.0024x over previous
//
#include <hip/hip_runtime.h>
#include <hip/hip_fp16.h>

// Problem: Topo_60653528154131
//   x:[256,3,256,25] f32, centres:[64,2] f32, sharpness:[64,2] f32 -> out:[64] f32
//
// FINAL (R8 revert): 4 kernels — separate graph nodes are the cheap grid barrier
// (measured: cooperative grid.sync() ~26 us/barrier on 8 XCDs, R7; last-block
// takeover neutral + rocprof-replay-fragile, R9).
//   K1 k_mean     : m[n,v] = mean_{c,t} x  (HBM-bound) + INF-init of Mp region
//   K2 k_dist     : feat (redundant per block), D2 row -> D16, row-min key -> rowKeyG,
//                   block 0 -> feat min/max
//   K3 k_contract : 256 blocks. Each block deterministically replays Boruvka round-1
//                   hooking from rowKeyG (ballot-rank renumber -> identical cmap in
//                   every block), folds ITS row of D16 into Mp[ca][cb] via GLOBAL
//                   atomicMin (storm distributed over 256 CUs). Block 0 additionally
//                   records round-1 deaths + comp count to global.
//   K4 k_mst      : 1 block. Load deaths/n from global, load Mp (n<=128) to LDS,
//                   Boruvka rounds 2+ on shrinking matrices,
//                   deaths = sqrt(D2)/(max-min), structure-element layer.
//
// ws layout:
//   m       [6400]  f32 @ 0
//   mm      [2]     u32 @ 25600
//   rowKeyG [256]   u32 @ 28672
//   deathsG [256]   f32 @ 29696
//   ncdcG   [2]     u32 @ 30720   (n after round 1, deaths count after round 1)
//   D16     [65536] u16 @ 65536   (fp16 bits of D^2)
//   Mp      [128*132] u32 @ 196608 (round-1 contracted matrix, stride 132)

#define WS_M    0
#define WS_MM   25600
#define WS_RK   28672
#define WS_DTH  29696
#define WS_NCDC 30720
#define WS_D16  65536
#define WS_MP   196608

#define INF32 0xFFFFFFFFu
#define MPSTR 132

// ---------------- K1: channel+time mean + Mp INF-init ----------------
__global__ void k_mean(const float* __restrict__ x, float* __restrict__ m,
                       unsigned int* __restrict__ Mp) {
    const int n = blockIdx.x;
    const int tid = threadIdx.x;
    if (tid < 66) Mp[n * 66 + tid] = INF32;   // 256*66 = 16896 = 128*132 exactly
    __shared__ float sums[25];
    if (tid < 25) sums[tid] = 0.0f;
    __syncthreads();
    if (tid < 200) {
        const float* base = x + (long)n * 19200 + 4 * tid;
        float a0 = 0.f, a1 = 0.f, a2 = 0.f, a3 = 0.f;
        #pragma unroll
        for (int i = 0; i < 24; ++i) {
            float4 v = *reinterpret_cast<const float4*>(base + 800 * i);
            a0 += v.x; a1 += v.y; a2 += v.z; a3 += v.w;
        }
        const int v0 = (4 * tid) % 25;
        atomicAdd(&sums[v0], a0);
        atomicAdd(&sums[(v0 + 1) % 25], a1);
        atomicAdd(&sums[(v0 + 2) % 25], a2);
        atomicAdd(&sums[(v0 + 3) % 25], a3);
    }
    __syncthreads();
    if (tid < 25) m[n * 25 + tid] = sums[tid] * (1.0f / 768.0f);
}

// wave64 min-reduce step via DPP: invalid lanes keep old=INF
template <int CTRL>
__device__ __forceinline__ unsigned int dpp_min_step(unsigned int v) {
    unsigned int t = (unsigned int)__builtin_amdgcn_update_dpp(
        (int)0xFFFFFFFF, (int)v, CTRL, 0xF, 0xF, false);
    return (t < v) ? t : v;
}

// ---------------- K2: feat + D2 row + row-min key + minmax ----------------
__global__ void __launch_bounds__(256) k_dist(const float* __restrict__ m,
                                              unsigned short* __restrict__ D16,
                                              unsigned int* __restrict__ rowKeyG,
                                              unsigned int* __restrict__ mm) {
    __shared__ float mS[6400];
    __shared__ float featS[6400];
    __shared__ unsigned int bmin, bmax;
    __shared__ unsigned int wred[4];
    const int i = blockIdx.x;
    const int t = threadIdx.x;
    if (t == 0) { bmin = 0x7F800000u; bmax = 0u; }
    #pragma unroll
    for (int it = 0; it < 7; ++it) {
        int o = it * 256 + t;
        if (o < 1600) reinterpret_cast<float4*>(mS)[o] =
            reinterpret_cast<const float4*>(m)[o];
    }
    __syncthreads();
    float r[25];
    #pragma unroll
    for (int v = 0; v < 25; ++v) r[v] = mS[t * 25 + v];
    float S1 = 0.f, S2 = 0.f;
    #pragma unroll
    for (int v = 0; v < 25; ++v) { S1 += r[v]; S2 += r[v] * r[v]; }
    float fmn = 1e30f, fmx = -1e30f;
    #pragma unroll
    for (int w = 0; w < 25; ++w) {
        float q = S2 - 2.f * r[w] * S1 + 25.f * r[w] * r[w];
        q = fmaxf(q, 0.f);
        float f = sqrtf(q);
        featS[t * 25 + w] = f;
        fmn = fminf(fmn, f); fmx = fmaxf(fmx, f);
    }
    if (i == 0) {
        atomicMin(&bmin, __float_as_uint(fmn));  // f>=0: uint order == float order
        atomicMax(&bmax, __float_as_uint(fmx));
    }
    __syncthreads();
    if (i == 0 && t == 0) { mm[0] = bmin; mm[1] = bmax; }
    float fi[25];
    #pragma unroll
    for (int v = 0; v < 25; ++v) fi[v] = featS[i * 25 + v];
    float s = 0.f;
    #pragma unroll
    for (int v = 0; v < 25; ++v) { float d = fi[v] - featS[t * 25 + v]; s += d * d; }
    const unsigned int w16 = (unsigned int)__half_as_ushort(__float2half(s));
    D16[i * 256 + t] = (unsigned short)w16;
    const unsigned int lo = (i < t) ? i : t, hi = (i < t) ? t : i;
    unsigned int key = (t == i) ? INF32 : ((w16 << 16) | (lo << 8) | hi);
    key = dpp_min_step<0x111>(key);
    key = dpp_min_step<0x112>(key);
    key = dpp_min_step<0x114>(key);
    key = dpp_min_step<0x118>(key);
    key = dpp_min_step<0x142>(key);
    key = dpp_min_step<0x143>(key);
    if ((t & 63) == 63) wred[t >> 6] = key;
    __syncthreads();
    if (t == 0) {
        unsigned int b0 = wred[0] < wred[1] ? wred[0] : wred[1];
        unsigned int b1 = wred[2] < wred[3] ? wred[2] : wred[3];
        rowKeyG[i] = b0 < b1 ? b0 : b1;
    }
}

// ---------------- wave0 Boruvka phase (DETERMINISTIC) ----------------
// hook -> 2-cycle break (optional death record) -> async pointer jump ->
// ballot-rank renumber (deterministic: identical cmap/nc in every block).
// Wave-0 lanes only; no __syncthreads inside.
template <bool RECORD>
__device__ __forceinline__ void wave0_phase(int n, int lane,
        unsigned int* rowKeyS, unsigned char* parentS, unsigned char* newidS,
        unsigned char* cmapS, float* deaths, unsigned int* ncS, unsigned int* dcS) {
    unsigned int par[4];
    #pragma unroll
    for (int s = 0; s < 4; ++s) {         // hook
        const int i = lane + 64 * s;
        if (i < n) {
            const unsigned int rk = rowKeyS[i];
            const unsigned int u = (rk >> 8) & 0xFFu, v = rk & 0xFFu;
            unsigned int p = (u == (unsigned int)i) ? v : u;
            if (rk == INF32) p = (unsigned int)i;  // safety; complete graph: unused
            par[s] = p;
            parentS[i] = (unsigned char)p;
        }
    }
    #pragma unroll
    for (int s = 0; s < 4; ++s) {         // break mutual 2-cycles
        const int i = lane + 64 * s;
        if (i < n) {
            const unsigned int p = par[s];
            if (p != (unsigned int)i) {
                if (parentS[p] == (unsigned char)i && (unsigned int)i < p) {
                    parentS[i] = (unsigned char)i;   // winner stays root, no death
                } else if (RECORD) {
                    const unsigned int d = atomicAdd(dcS, 1u);
                    const unsigned int rk = rowKeyS[i];
                    deaths[d] = sqrtf(__half2float(__ushort_as_half(
                        (unsigned short)(rk >> 16))));
                }
            }
        }
    }
    for (;;) {                            // async pointer jump (deterministic fixpoint)
        bool ch = false;
        #pragma unroll
        for (int s = 0; s < 4; ++s) {
            const int i = lane + 64 * s;
            if (i < n) {
                const unsigned char p0 = parentS[i];
                const unsigned char np = parentS[p0];
                if (np != p0) { ch = true; parentS[i] = np; }
            }
        }
        if (__ballot(ch) == 0ull) break;
    }
    // ballot-rank renumber; below = lanes strictly below me (well-defined, lane<=63)
    bool isr[4];
    #pragma unroll
    for (int s = 0; s < 4; ++s) {
        const int i = lane + 64 * s;
        isr[s] = (i < n) && (parentS[i] == (unsigned char)i);
    }
    unsigned int base = 0;
    const unsigned long long below = (1ull << lane) - 1ull;
    #pragma unroll
    for (int s = 0; s < 4; ++s) {
        const unsigned long long mask = __ballot(isr[s]);   // uniform execution
        if (isr[s]) {
            const int i = lane + 64 * s;
            newidS[i] = (unsigned char)(base + __popcll(mask & below));
        }
        base += (unsigned int)__popcll(mask);
    }
    if (lane == 0) *ncS = base;
    #pragma unroll
    for (int s = 0; s < 4; ++s) {
        const int i = lane + 64 * s;
        if (i < n) cmapS[i] = newidS[parentS[i]];
    }
}

// ---------------- K3: distributed round-1 contraction (+ deaths from block 0) ----
__global__ void __launch_bounds__(256) k_contract(const unsigned short* __restrict__ D16g,
                                                  const unsigned int* __restrict__ rowKeyG,
                                                  unsigned int* __restrict__ Mp,
                                                  float* __restrict__ deathsG,
                                                  unsigned int* __restrict__ ncdcG) {
    __shared__ unsigned int rowKeyS[256];
    __shared__ unsigned char parentS[256], newidS[256], cmapS[256];
    __shared__ unsigned int ncS, dcS;
    __shared__ float deathsS[256];
    const int tid = threadIdx.x;
    const int b = blockIdx.x;
    rowKeyS[tid] = rowKeyG[tid];
    if (tid == 0) dcS = 0;
    __syncthreads();
    if (tid < 64) {
        if (b == 0)
            wave0_phase<true>(256, tid, rowKeyS, parentS, newidS, cmapS,
                              deathsS, &ncS, &dcS);
        else
            wave0_phase<false>(256, tid, rowKeyS, parentS, newidS, cmapS,
                               nullptr, &ncS, nullptr);
    }
    __syncthreads();
    if (b == 0) {   // publish round-1 deaths + counts (deterministic multiset)
        if (tid < dcS) deathsG[tid] = deathsS[tid];
        if (tid == 0) { ncdcG[0] = ncS; ncdcG[1] = dcS; }
    }
    // fold row b into Mp via global atomicMin (distributed across 256 CUs)
    const unsigned int ca = cmapS[b];
    const unsigned int cb = cmapS[tid];
    if (ca != cb) {
        const unsigned int w16 = (unsigned int)D16g[b * 256 + tid];
        const unsigned int lo = ca < cb ? ca : cb;
        const unsigned int hi = ca < cb ? cb : ca;
        atomicMin(&Mp[ca * MPSTR + cb], (w16 << 16) | (lo << 8) | hi);
    }
}

// ---------------- K4: Boruvka rounds 2+ on contracted matrix + structure layer ----
#define SA 132   // u32 stride, buffer A (cap 128 rows)
#define SB 68    // u32 stride, buffer B (cap 64 rows)
#define OFF_B (128 * SA)

__global__ void __launch_bounds__(1024) k_mst(const unsigned int* __restrict__ Mp,
                                              const float* __restrict__ deathsG,
                                              const unsigned int* __restrict__ ncdcG,
                                              const unsigned int* __restrict__ mm,
                                              const float* __restrict__ centres,
                                              const float* __restrict__ sharp,
                                              float* __restrict__ out) {
    __shared__ unsigned int Mb[128 * SA + 64 * SB];   // 85 KB ping-pong
    __shared__ unsigned int rowKeyS[256];
    __shared__ unsigned char parentS[256], newidS[256], cmapS[256];
    __shared__ unsigned int ncS, dcS;
    __shared__ float deaths[256];
    __shared__ float outpart[1024];
    const int tid = threadIdx.x;

    // round-1 results from k_contract: n, deaths so far
    if (tid == 0) { ncS = ncdcG[0]; dcS = ncdcG[1]; }
    if (tid < 256) deaths[tid] = deathsG[tid];   // only [0,dcS) meaningful
    __syncthreads();
    int n = (int)ncS;

    // load contracted matrix Mp (n x n, stride MPSTR==SA) into buffer A
    for (int idx = tid; idx < n * SA; idx += 1024) Mb[idx] = Mp[idx];
    __syncthreads();

    // rounds 2+ (bounded: Boruvka on <=256 nodes needs <=8 rounds; 12 = hang guard)
    int srcOff = 0, srcStr = SA, dstOff = OFF_B, dstStr = SB;
    for (int round = 0; round < 12 && n > 1; ++round) {
        if (tid < n) rowKeyS[tid] = INF32;
        __syncthreads();
        if (tid < 8 * n) {                 // scan: 8 threads per row
            const int a = tid >> 3, sub = tid & 7;
            const unsigned int* row = &Mb[srcOff + a * srcStr];
            unsigned int best = INF32;
            for (int b2 = sub; b2 < n; b2 += 8) {
                const unsigned int v = row[b2];
                best = v < best ? v : best;
            }
            if (best != INF32) atomicMin(&rowKeyS[a], best);
        }
        __syncthreads();
        if (tid < 64)
            wave0_phase<true>(n, tid, rowKeyS, parentS, newidS, cmapS,
                              deaths, &ncS, &dcS);
        __syncthreads();
        const int nc = (int)ncS;
        if (nc > 1) {                      // contract src -> dst
            for (int w = tid; w < nc * dstStr; w += 1024) Mb[dstOff + w] = INF32;
            __syncthreads();
            if (tid < 8 * n) {
                const int a = tid >> 3, sub = tid & 7;
                const unsigned int ca = cmapS[a];
                const unsigned int* row = &Mb[srcOff + a * srcStr];
                for (int b2 = sub; b2 < n; b2 += 8) {
                    const unsigned int cb = cmapS[b2];
                    const unsigned int v = row[b2];
                    if (ca != cb && v != INF32) {
                        const unsigned int lo = ca < cb ? ca : cb;
                        const unsigned int hi = ca < cb ? cb : ca;
                        atomicMin(&Mb[dstOff + ca * dstStr + cb],
                                  (v & 0xFFFF0000u) | (lo << 8) | hi);
                    }
                }
            }
            __syncthreads();
        }
        const int t1 = srcOff; srcOff = dstOff; dstOff = t1;
        const int t2 = srcStr; srcStr = dstStr; dstStr = t2;
        n = nc;
    }

    // structure-element layer: out[k] = sum_i exp(-c0^2 s0^2 - (d_i-c1)^2 s1^2)
    const float mn = __uint_as_float(mm[0]);
    const float mx = __uint_as_float(mm[1]);
    const float inv = 1.0f / (mx - mn);
    const int k = tid & 63;
    const int part = tid >> 6;
    const float c0 = centres[2 * k], c1 = centres[2 * k + 1];
    const float s0 = sharp[2 * k],   s1 = sharp[2 * k + 1];
    const float t0 = c0 * c0 * s0 * s0;
    const float s1sq = s1 * s1;
    float acc = 0.f;
    for (int idx = part; idx < 255; idx += 16) {
        const float d = deaths[idx] * inv - c1;
        acc += __expf(-(t0 + d * d * s1sq));
    }
    outpart[tid] = acc;
    __syncthreads();
    if (tid < 64) {
        float s = 0.f;
        #pragma unroll
        for (int pp = 0; pp < 16; ++pp) s += outpart[tid + 64 * pp];
        out[tid] = s;
    }
}

extern "C" void kernel_launch(void* const* d_in, const int* in_sizes, int n_in,
                              void* d_out, int out_size, void* d_ws, size_t ws_size,
                              hipStream_t stream) {
    const float* x       = (const float*)d_in[0];
    const float* centres = (const float*)d_in[1];
    const float* sharp   = (const float*)d_in[2];
    float* out = (float*)d_out;
    char* ws = (char*)d_ws;
    float*          m    = (float*)(ws + WS_M);
    unsigned int*   mm   = (unsigned int*)(ws + WS_MM);
    unsigned int*   rk   = (unsigned int*)(ws + WS_RK);
    float*          dth  = (float*)(ws + WS_DTH);
    unsigned int*   ncdc = (unsigned int*)(ws + WS_NCDC);
    unsigned short* D16  = (unsigned short*)(ws + WS_D16);
    unsigned int*   Mp   = (unsigned int*)(ws + WS_MP);

    k_mean<<<256, 256, 0, stream>>>(x, m, Mp);
    k_dist<<<256, 256, 0, stream>>>(m, D16, rk, mm);
    k_contract<<<256, 256, 0, stream>>>(D16, rk, Mp, dth, ncdc);
    k_mst<<<1, 1024, 0, stream>>>(Mp, dth, ncdc, mm, centres, sharp, out);
}